// Round 1
// baseline (3727.228 us; speedup 1.0000x reference)
//
#include <hip/hip_runtime.h>
#include <stdint.h>

// DCRNN forward, MI355X. Strategy:
//  - Precompute A[4] = {S0, 2*S0^2-I, S1, 2*S1^2-I} in bf16 (Chebyshev collapse).
//  - One kernel per diffusion-conv: block = (batch, 32-row n-tile); full xs^T
//    staged in LDS (bf16); 4 hop GEMMs + 5-slice projection fused via
//    mfma_f32_16x16x32_bf16 (fp32 accum). Gates/candidate/GRU epilogues fused.
//  - 96 dc-kernel launches + 2 prep + 3 memsets per call. All fp32 state.

typedef short short8 __attribute__((ext_vector_type(8)));
typedef float f32x4 __attribute__((ext_vector_type(4)));

#define DEVI __device__ __forceinline__

DEVI unsigned short f2bf(float x) {
  unsigned int u = __builtin_bit_cast(unsigned int, x);
  u += 0x7FFFu + ((u >> 16) & 1u);       // RNE
  return (unsigned short)(u >> 16);
}

// ---------------- prep kernels ----------------
__global__ void prep_A(const float* __restrict__ s0, const float* __restrict__ s1,
                       unsigned short* __restrict__ A) {
  const int i = blockIdx.x, s = blockIdx.y, j = threadIdx.x;
  const float* S = s ? s1 : s0;
  float acc = 0.f;
  for (int k = 0; k < 256; ++k) acc += S[i * 256 + k] * S[k * 256 + j];
  A[(2 * s + 0) * 65536 + i * 256 + j] = f2bf(S[i * 256 + j]);
  A[(2 * s + 1) * 65536 + i * 256 + j] = f2bf(2.f * acc - (i == j ? 1.f : 0.f));
}

struct WD { const float* src; unsigned short* dst; int F, O, FP; };
struct WD8 { WD d[8]; };

// Wpack[o][m*FP + f] = W[f, m, o] (bf16, zero-padded f in [F, FP))
__global__ void prep_W(WD8 ds) {
  WD w = ds.d[blockIdx.y];
  const int KP = 5 * w.FP;
  const int tot = w.O * KP;
  const int e = blockIdx.x * 256 + threadIdx.x;
  if (e >= tot) return;
  const int o = e / KP, k = e - o * KP;
  const int m = k / w.FP, f = k - m * w.FP;
  const float v = (f < w.F) ? w.src[(f * 5 + m) * w.O + o] : 0.f;
  w.dst[e] = f2bf(v);
}

// ---------------- fused diffusion-conv kernel ----------------
// MODE 0: gates  (sigmoid; writes rh = r*h and u)
// MODE 1: cand   (tanh; reads u,h; writes h_new)
// MODE 2: cand + final decoder projection (writes d_out slice and xnext)
template<int IND, int FP, int O, int MODE>
__launch_bounds__(256, 2)
__global__ void dc_kernel(const float* __restrict__ xptr, int xsB,
                          const float* __restrict__ hbuild,   // h (gates) or r*h (cand)
                          const unsigned short* __restrict__ Amats,
                          const unsigned short* __restrict__ Wp,
                          const float* __restrict__ bias,
                          const float* __restrict__ hprev,
                          float* __restrict__ rh_out,
                          float* __restrict__ u_buf,
                          float* __restrict__ h_out,
                          const float* __restrict__ projW,
                          const float* __restrict__ projB,
                          float* __restrict__ outp, int osB,
                          float* __restrict__ xnext)
{
  constexpr int F   = IND + 64;
  constexpr int KP  = 5 * FP;
  constexpr int XS  = 264;            // xsT row stride (elems): 528B, 16B-aligned, ~2-way banks
  constexpr int HS  = 136;            // Hbuf row stride: 272B, 16B-aligned
  constexpr int NFT = FP / 16;
  constexpr int NOT_ = O / 16;
  constexpr int FT_W = (NFT + 3) / 4;
  constexpr int OT_W = (NOT_ + 3) / 4;

  __shared__ __align__(16) unsigned short xsT[FP * XS];   // [f][n'] transposed
  __shared__ __align__(16) unsigned short Hbuf[32 * HS];  // [n-local][f] row-major

  const int tid = threadIdx.x;
  const int wv = tid >> 6, ln = tid & 63;
  const int l15 = ln & 15, l4 = ln >> 4;
  const int b = blockIdx.y;
  const int n0 = blockIdx.x * 32;

  // ---- build xs^T (all 256 rows) + Hbuf = xs rows [n0,n0+32) (identity slice) ----
  {
    const float* hb = hbuild + b * 16384;
    const int h4 = (tid & 15) * 4;
    const int ng = tid >> 4;
    for (int nn = 0; nn < 16; ++nn) {
      const int n = ng * 16 + nn;
      f32x4 v = *reinterpret_cast<const f32x4*>(hb + n * 64 + h4);
#pragma unroll
      for (int i = 0; i < 4; ++i) {
        unsigned short s = f2bf(v[i]);
        xsT[(IND + h4 + i) * XS + n] = s;
        if ((unsigned)(n - n0) < 32u) Hbuf[(n - n0) * HS + IND + h4 + i] = s;
      }
    }
  }
  if (IND == 64) {
    const float* xb = xptr + b * xsB;
    const int h4 = (tid & 15) * 4;
    const int ng = tid >> 4;
    for (int nn = 0; nn < 16; ++nn) {
      const int n = ng * 16 + nn;
      f32x4 v = *reinterpret_cast<const f32x4*>(xb + n * 64 + h4);
#pragma unroll
      for (int i = 0; i < 4; ++i) {
        unsigned short s = f2bf(v[i]);
        xsT[(h4 + i) * XS + n] = s;
        if ((unsigned)(n - n0) < 32u) Hbuf[(n - n0) * HS + h4 + i] = s;
      }
    }
  } else {
    const float* xb = xptr + b * xsB;
    for (int e = tid; e < 256 * IND; e += 256) {
      const int n = e / IND, i = e - n * IND;
      unsigned short s = f2bf(xb[e]);
      xsT[i * XS + n] = s;
      if ((unsigned)(n - n0) < 32u) Hbuf[(n - n0) * HS + i] = s;
    }
  }
  if (F < FP) {
    for (int e = tid; e < (FP - F) * 256; e += 256) {
      const int f = F + (e >> 8), n = e & 255;
      xsT[f * XS + n] = 0;
      if ((unsigned)(n - n0) < 32u) Hbuf[(n - n0) * HS + f] = 0;
    }
  }
  __syncthreads();

  f32x4 pacc[2][OT_W];
#pragma unroll
  for (int rt = 0; rt < 2; ++rt)
#pragma unroll
    for (int oi = 0; oi < OT_W; ++oi) pacc[rt][oi] = 0.f;

  // projection partial: out += Hbuf(.) @ Wp[:, m*FP : (m+1)*FP]^T
  auto proj_step = [&](int m) {
#pragma unroll
    for (int k0 = 0; k0 < FP; k0 += 32) {
      short8 af[2];
#pragma unroll
      for (int rt = 0; rt < 2; ++rt)
        af[rt] = *reinterpret_cast<const short8*>(&Hbuf[(rt * 16 + l15) * HS + k0 + l4 * 8]);
#pragma unroll
      for (int oi = 0; oi < OT_W; ++oi) {
        const int ot = wv + 4 * oi;
        if (ot < NOT_) {
          short8 bf = *reinterpret_cast<const short8*>(&Wp[(ot * 16 + l15) * KP + m * FP + k0 + l4 * 8]);
#pragma unroll
          for (int rt = 0; rt < 2; ++rt)
            pacc[rt][oi] = __builtin_amdgcn_mfma_f32_16x16x32_bf16(af[rt], bf, pacc[rt][oi], 0, 0, 0);
        }
      }
    }
  };

  proj_step(0);  // identity slice

  for (int mi = 0; mi < 4; ++mi) {
    const unsigned short* Am = Amats + mi * 65536;
    f32x4 hacc[2][FT_W];
#pragma unroll
    for (int rt = 0; rt < 2; ++rt)
#pragma unroll
      for (int fi = 0; fi < FT_W; ++fi) hacc[rt][fi] = 0.f;

#pragma unroll
    for (int k0 = 0; k0 < 256; k0 += 32) {
      short8 af[2];
#pragma unroll
      for (int rt = 0; rt < 2; ++rt)
        af[rt] = *reinterpret_cast<const short8*>(&Am[(n0 + rt * 16 + l15) * 256 + k0 + l4 * 8]);
#pragma unroll
      for (int fi = 0; fi < FT_W; ++fi) {
        const int ft = wv + 4 * fi;
        if (ft < NFT) {
          short8 bf = *reinterpret_cast<const short8*>(&xsT[(ft * 16 + l15) * XS + k0 + l4 * 8]);
#pragma unroll
          for (int rt = 0; rt < 2; ++rt)
            hacc[rt][fi] = __builtin_amdgcn_mfma_f32_16x16x32_bf16(af[rt], bf, hacc[rt][fi], 0, 0, 0);
        }
      }
    }
    __syncthreads();   // previous proj_step readers of Hbuf done
#pragma unroll
    for (int fi = 0; fi < FT_W; ++fi) {
      const int ft = wv + 4 * fi;
      if (ft < NFT) {
#pragma unroll
        for (int rt = 0; rt < 2; ++rt)
#pragma unroll
          for (int j = 0; j < 4; ++j)
            Hbuf[(rt * 16 + l4 * 4 + j) * HS + ft * 16 + l15] = f2bf(hacc[rt][fi][j]);
      }
    }
    __syncthreads();
    proj_step(mi + 1);
  }

  if (MODE == 2) __syncthreads();                      // before hrow overlays Hbuf
  float* hrow = reinterpret_cast<float*>(Hbuf);        // [32][68] fp32 overlay (MODE 2)

  const int bN = b * 16384;
#pragma unroll
  for (int oi = 0; oi < OT_W; ++oi) {
    const int ot = wv + 4 * oi;
    if (ot >= NOT_) continue;
    const int o = ot * 16 + l15;
    const float bs = bias[o];
#pragma unroll
    for (int rt = 0; rt < 2; ++rt) {
#pragma unroll
      for (int j = 0; j < 4; ++j) {
        const int n = n0 + rt * 16 + l4 * 4 + j;
        const float val = pacc[rt][oi][j] + bs;
        if (MODE == 0) {
          const float g = 1.f / (1.f + __expf(-val));
          if (o < 64) rh_out[bN + n * 64 + o] = g * hprev[bN + n * 64 + o];
          else        u_buf[bN + n * 64 + (o - 64)] = g;
        } else {
          const float c  = tanhf(val);
          const float u  = u_buf[bN + n * 64 + o];
          const float hp = hprev[bN + n * 64 + o];
          const float hn = u * hp + (1.f - u) * c;
          h_out[bN + n * 64 + o] = hn;
          if (MODE == 2) hrow[(n - n0) * 68 + o] = hn;
        }
      }
    }
  }

  if (MODE == 2) {
    __syncthreads();
    if (tid < 32) {
      float acc = projB[0];
      const float* hr = hrow + tid * 68;
#pragma unroll
      for (int hid = 0; hid < 64; ++hid) acc += hr[hid] * projW[hid];
      outp[b * osB + n0 + tid] = acc;
      xnext[b * 256 + n0 + tid] = acc;
    }
  }
}

// ---------------- host ----------------
extern "C" void kernel_launch(void* const* d_in, const int* in_sizes, int n_in,
                              void* d_out, int out_size, void* d_ws, size_t ws_size,
                              hipStream_t stream)
{
  const float* enc_in = (const float*)d_in[0];
  const float* sup0 = (const float*)d_in[2];
  const float* sup1 = (const float*)d_in[3];
  const float* Wg_e0 = (const float*)d_in[4];  const float* bg_e0 = (const float*)d_in[5];
  const float* Wc_e0 = (const float*)d_in[6];  const float* bc_e0 = (const float*)d_in[7];
  const float* Wg_e1 = (const float*)d_in[8];  const float* bg_e1 = (const float*)d_in[9];
  const float* Wc_e1 = (const float*)d_in[10]; const float* bc_e1 = (const float*)d_in[11];
  const float* Wg_d0 = (const float*)d_in[12]; const float* bg_d0 = (const float*)d_in[13];
  const float* Wc_d0 = (const float*)d_in[14]; const float* bc_d0 = (const float*)d_in[15];
  const float* Wg_d1 = (const float*)d_in[16]; const float* bg_d1 = (const float*)d_in[17];
  const float* Wc_d1 = (const float*)d_in[18]; const float* bc_d1 = (const float*)d_in[19];
  const float* prW = (const float*)d_in[20];   const float* prB = (const float*)d_in[21];
  float* out = (float*)d_out;

  char* ws = (char*)d_ws;
  size_t off = 0;
  auto carve = [&](size_t bytes) -> char* {
    char* p = ws + off;
    off += (bytes + 255) & ~(size_t)255;
    return p;
  };
  unsigned short* A     = (unsigned short*)carve(4 * 65536 * 2);
  unsigned short* Pg_e0 = (unsigned short*)carve(128 * 480 * 2);
  unsigned short* Pc_e0 = (unsigned short*)carve(64 * 480 * 2);
  unsigned short* Pg_e1 = (unsigned short*)carve(128 * 640 * 2);
  unsigned short* Pc_e1 = (unsigned short*)carve(64 * 640 * 2);
  unsigned short* Pg_d0 = (unsigned short*)carve(128 * 480 * 2);
  unsigned short* Pc_d0 = (unsigned short*)carve(64 * 480 * 2);
  unsigned short* Pg_d1 = (unsigned short*)carve(128 * 640 * 2);
  unsigned short* Pc_d1 = (unsigned short*)carve(64 * 640 * 2);
  float* h0[2] = {(float*)carve(4194304), (float*)carve(4194304)};
  float* h1[2] = {(float*)carve(4194304), (float*)carve(4194304)};
  float* rh = (float*)carve(4194304);
  float* ub = (float*)carve(4194304);
  float* xd[2] = {(float*)carve(65536), (float*)carve(65536)};

  hipMemsetAsync(h0[0], 0, 4194304, stream);
  hipMemsetAsync(h1[0], 0, 4194304, stream);
  hipMemsetAsync(xd[0], 0, 65536, stream);

  prep_A<<<dim3(256, 2), 256, 0, stream>>>(sup0, sup1, A);
  WD8 wd;
  wd.d[0] = {Wg_e0, Pg_e0, 66, 128, 96};
  wd.d[1] = {Wc_e0, Pc_e0, 66, 64, 96};
  wd.d[2] = {Wg_e1, Pg_e1, 128, 128, 128};
  wd.d[3] = {Wc_e1, Pc_e1, 128, 64, 128};
  wd.d[4] = {Wg_d0, Pg_d0, 65, 128, 96};
  wd.d[5] = {Wc_d0, Pc_d0, 65, 64, 96};
  wd.d[6] = {Wg_d1, Pg_d1, 128, 128, 128};
  wd.d[7] = {Wc_d1, Pc_d1, 128, 64, 128};
  prep_W<<<dim3(320, 8), 256, 0, stream>>>(wd);

  dim3 grd(8, 64), blk(256);
  int c0 = 0, c1 = 0;

  // encoder (step-interleaved layers; identical math to layer-wise scan)
  for (int t = 0; t < 12; ++t) {
    const float* x0 = enc_in + t * 512;
    dc_kernel<2, 96, 128, 0><<<grd, blk, 0, stream>>>(x0, 6144, h0[c0], A, Pg_e0, bg_e0, h0[c0],
        rh, ub, nullptr, nullptr, nullptr, nullptr, 0, nullptr);
    dc_kernel<2, 96, 64, 1><<<grd, blk, 0, stream>>>(x0, 6144, rh, A, Pc_e0, bc_e0, h0[c0],
        nullptr, ub, h0[c0 ^ 1], nullptr, nullptr, nullptr, 0, nullptr);
    c0 ^= 1;
    dc_kernel<64, 128, 128, 0><<<grd, blk, 0, stream>>>(h0[c0], 16384, h1[c1], A, Pg_e1, bg_e1, h1[c1],
        rh, ub, nullptr, nullptr, nullptr, nullptr, 0, nullptr);
    dc_kernel<64, 128, 64, 1><<<grd, blk, 0, stream>>>(h0[c0], 16384, rh, A, Pc_e1, bc_e1, h1[c1],
        nullptr, ub, h1[c1 ^ 1], nullptr, nullptr, nullptr, 0, nullptr);
    c1 ^= 1;
  }

  // decoder (go = zeros; feedback via xd ping-pong; final proj fused in MODE 2)
  int cx = 0;
  for (int t = 0; t < 12; ++t) {
    dc_kernel<1, 96, 128, 0><<<grd, blk, 0, stream>>>(xd[cx], 256, h0[c0], A, Pg_d0, bg_d0, h0[c0],
        rh, ub, nullptr, nullptr, nullptr, nullptr, 0, nullptr);
    dc_kernel<1, 96, 64, 1><<<grd, blk, 0, stream>>>(xd[cx], 256, rh, A, Pc_d0, bc_d0, h0[c0],
        nullptr, ub, h0[c0 ^ 1], nullptr, nullptr, nullptr, 0, nullptr);
    c0 ^= 1;
    dc_kernel<64, 128, 128, 0><<<grd, blk, 0, stream>>>(h0[c0], 16384, h1[c1], A, Pg_d1, bg_d1, h1[c1],
        rh, ub, nullptr, nullptr, nullptr, nullptr, 0, nullptr);
    dc_kernel<64, 128, 64, 2><<<grd, blk, 0, stream>>>(h0[c0], 16384, rh, A, Pc_d1, bc_d1, h1[c1],
        nullptr, ub, h1[c1 ^ 1], prW, prB, out + t * 256, 3072, xd[cx ^ 1]);
    c1 ^= 1; cx ^= 1;
  }
}